// Round 9
// baseline (147.239 us; speedup 1.0000x reference)
//
#include <hip/hip_runtime.h>

// Problem constants (B=4, C_IN=C_OUT=64, H=W=128, K=3, stride=1, pad=1)
// Harness I/O fp32. Internally: NHWC bf16 x, bf16 MFMA for both convs.
// NOTE (round ledger R2-R8): total ~= k_main + ~7us own aux + ~70us FIXED
// harness overhead (reset/graph).  k_main is the only real lever.
#define HW   16384
#define NPX  65536

typedef unsigned short u16;
typedef unsigned int   u32;
typedef short bf16x8 __attribute__((ext_vector_type(8)));
typedef float f32x4  __attribute__((ext_vector_type(4)));

__device__ __forceinline__ u16 f2b(float f) {               // fp32->bf16 RNE
    u32 u = __float_as_uint(f);
    return (u16)((u + 0x7FFFu + ((u >> 16) & 1u)) >> 16);
}
__device__ __forceinline__ float blo(u32 u) { return __uint_as_float(u << 16); }
__device__ __forceinline__ float bhi(u32 u) { return __uint_as_float(u & 0xffff0000u); }

// bilinear blend of one u32 (2 bf16 channels) x 4 corners -> packed bf16 pair
// pack via v_perm_b32: dst = {hi.b3, hi.b2, lo.b3, lo.b2} (round-half-up)
__device__ __forceinline__ u32 comb(u32 a00, u32 a01, u32 a10, u32 a11,
                                    float w00, float w01, float w10, float w11) {
    float lo = fmaf(w11, blo(a11), fmaf(w10, blo(a10), fmaf(w01, blo(a01), w00 * blo(a00))));
    float hi = fmaf(w11, bhi(a11), fmaf(w10, bhi(a10), fmaf(w01, bhi(a01), w00 * bhi(a00))));
    return __builtin_amdgcn_perm(__float_as_uint(hi) + 0x8000u,
                                 __float_as_uint(lo) + 0x8000u, 0x07060302u);
}
__device__ __forceinline__ bf16x8 comb4(int4 v00, int4 v01, int4 v10, int4 v11,
                                        float w00, float w01, float w10, float w11) {
    int4 r;
    r.x = comb(v00.x, v01.x, v10.x, v11.x, w00, w01, w10, w11);
    r.y = comb(v00.y, v01.y, v10.y, v11.y, w00, w01, w10, w11);
    r.z = comb(v00.z, v01.z, v10.z, v11.z, w00, w01, w10, w11);
    r.w = comb(v00.w, v01.w, v10.w, v11.w, w00, w01, w10, w11);
    return __builtin_bit_cast(bf16x8, r);
}

#define MFMA __builtin_amdgcn_mfma_f32_16x16x32_bf16

// ---------------------------------------------------------------------------
// k_pre: blocks [0,512): NCHW fp32 -> NHWC bf16, 128-px tiles (coalesced).
// Blocks [512,539): weight prep to B-frag-linear bf16.
// Block 539: zero BN partial bins.
// ---------------------------------------------------------------------------
__global__ __launch_bounds__(256)
void k_pre(const float* __restrict__ x, const float* __restrict__ dw,
           const float* __restrict__ ow, u16* __restrict__ xh,
           u16* __restrict__ wtd, u16* __restrict__ wto,
           float* __restrict__ sums) {
    int tid = threadIdx.x;
    int bid = blockIdx.x;
    if (bid >= 512) {
        if (bid == 539) {
            for (int i = tid; i < 1024; i += 256) sums[i] = 0.f;
            return;
        }
        int gid = (bid - 512) * 256 + tid;       // ---- weight prep ----
        if (gid >= 108 * 64) return;
        int fid = gid >> 6, lane = gid & 63;
        int mi = lane & 15, quad = lane >> 4;
        u32 w[4];
        if (fid < 72) {
            int tap = fid >> 3, rem = fid & 7;
            int ks = rem >> 2, nt = rem & 3;
            int n = nt * 16 + mi;
            int cb = ks * 32 + quad * 8;
#pragma unroll
            for (int i = 0; i < 4; ++i) {
                u32 lo = f2b(dw[(n * 64 + cb + 2 * i) * 9 + tap]);
                u32 hi = f2b(dw[(n * 64 + cb + 2 * i + 1) * 9 + tap]);
                w[i] = lo | (hi << 16);
            }
            *((int4*)wtd + (fid << 6) + lane) = make_int4(w[0], w[1], w[2], w[3]);
        } else {
            int f2 = fid - 72;
            int tap = f2 >> 2, rem = f2 & 3;
            int ks = rem >> 1, nt = rem & 1;
            int n = nt * 16 + mi;
            int cb = ks * 32 + quad * 8;
#pragma unroll
            for (int i = 0; i < 4; ++i) {
                u32 lo = (n < 18) ? f2b(ow[(n * 64 + cb + 2 * i) * 9 + tap]) : 0u;
                u32 hi = (n < 18) ? f2b(ow[(n * 64 + cb + 2 * i + 1) * 9 + tap]) : 0u;
                w[i] = lo | (hi << 16);
            }
            *((int4*)wto + (f2 << 6) + lane) = make_int4(w[0], w[1], w[2], w[3]);
        }
        return;
    }
    // ---- NCHW fp32 -> NHWC bf16, 128-px tile ----
    __shared__ u16 tile[64][138];
    int p0  = bid * 128;
    int b   = p0 >> 14;
    int hw0 = p0 & (HW - 1);
    int pxq = (tid & 31) * 4;
    int rr  = tid >> 5;
    const float* src = x + (size_t)b * 64 * HW + hw0 + pxq;
#pragma unroll
    for (int i = 0; i < 8; ++i) {
        int c = i * 8 + rr;
        float4 v = *(const float4*)(src + (size_t)c * HW);
        ushort4 h;
        h.x = f2b(v.x); h.y = f2b(v.y); h.z = f2b(v.z); h.w = f2b(v.w);
        *(ushort4*)&tile[c][pxq] = h;
    }
    __syncthreads();
    int sub = tid & 3;
#pragma unroll
    for (int j = 0; j < 2; ++j) {
        int px = j * 64 + (tid >> 2);
        u32 w[8];
#pragma unroll
        for (int t = 0; t < 8; ++t) {
            int c = sub * 16 + 2 * t;
            w[t] = (u32)tile[c][px] | ((u32)tile[c + 1][px] << 16);
        }
        u16* dst = xh + (size_t)(p0 + px) * 64 + sub * 16;
        *(int4*)dst       = make_int4(w[0], w[1], w[2], w[3]);
        *(int4*)(dst + 8) = make_int4(w[4], w[5], w[6], w[7]);
    }
}

// ---------------------------------------------------------------------------
// k_main: FUSED offset conv + deformable conv, ks-split, 2-TAP LOAD BATCHES.
// 2048 blocks x 256 thr; block = 32 px.  Wave = (ks, px-half): 16 px x 64
// out x 32 ch.  Phase 2 issues both taps' 8 corner loads before either
// tap's comb/MFMA (one vmcnt stall per tap-pair), pinned by sched_barrier.
// launch_bounds(256,5): VGPR cap ~102 for the batch buffers, 20 waves/CU.
// ---------------------------------------------------------------------------
__global__ __launch_bounds__(256, 5)
void k_main(const u16* __restrict__ xh, const u16* __restrict__ wto,
            const u16* __restrict__ wtd, const float* __restrict__ ob,
            float* __restrict__ out, float* __restrict__ sums) {
    __shared__ float offs[2][18][34];
    __shared__ float so[64][33];

    int tid = threadIdx.x;
    int vb  = (blockIdx.x & 7) * 256 + (blockIdx.x >> 3);   // XCD-contig
    int p0  = vb * 32;
    int b   = p0 >> 14;
    int hw0 = p0 & (HW - 1);
    int y   = hw0 >> 7;
    int x0  = hw0 & 127;
    int wave = tid >> 6, lane = tid & 63;
    int mi = lane & 15, quad = lane >> 4;
    int ks = wave >> 1;
    int m0 = (wave & 1) << 4;
    int xcol = x0 + m0 + mi;
    int koff = ks * 32 + quad * 8;
    const u16* xb = xh + (size_t)b * HW * 64;
    const bf16x8* WO = (const bf16x8*)wto;
    const bf16x8* WD = (const bf16x8*)wtd;

    // ---- phase 1: offset conv partial (this ks half), loads upfront ----
    int4 av[9];
#pragma unroll
    for (int tap = 0; tap < 9; ++tap) {
        int yy = y + tap / 3 - 1;
        int xx = xcol + tap % 3 - 1;
        int yc = min(max(yy, 0), 127), xc = min(max(xx, 0), 127);
        int4 a = *(const int4*)(xb + ((yc << 7) + xc) * 64 + koff);
        if (!(((unsigned)yy < 128u) && ((unsigned)xx < 128u)))
            a = make_int4(0, 0, 0, 0);
        av[tap] = a;
    }
    f32x4 oa0 = {0.f, 0.f, 0.f, 0.f}, oa1 = {0.f, 0.f, 0.f, 0.f};
#pragma unroll
    for (int tap = 0; tap < 9; ++tap) {
        bf16x8 af = __builtin_bit_cast(bf16x8, av[tap]);
        oa0 = MFMA(af, WO[((tap * 4 + ks * 2 + 0) << 6) + lane], oa0, 0, 0, 0);
        oa1 = MFMA(af, WO[((tap * 4 + ks * 2 + 1) << 6) + lane], oa1, 0, 0, 0);
    }
    {   // C layout: col = lane&15 = n, row = quad*4+r = px-in-wave-tile
        float bias0 = (ks == 0) ? ob[mi] : 0.f;
#pragma unroll
        for (int r = 0; r < 4; ++r)
            offs[ks][mi][m0 + quad * 4 + r] = oa0[r] + bias0;
        if (mi < 2) {
            float bias1 = (ks == 0) ? ob[16 + mi] : 0.f;
#pragma unroll
            for (int r = 0; r < 4; ++r)
                offs[ks][16 + mi][m0 + quad * 4 + r] = oa1[r] + bias1;
        }
    }
    __syncthreads();

    // ---- phase 2: deformable conv (this ks half), 2-tap load batches ----
    int pxl = m0 + mi;
    float offv[18];
#pragma unroll
    for (int m = 0; m < 18; ++m)
        offv[m] = offs[0][m][pxl] + offs[1][m][pxl];

    float fy = (float)y, fx = (float)xcol;
    f32x4 acc0 = {0.f,0.f,0.f,0.f}, acc1 = {0.f,0.f,0.f,0.f};
    f32x4 acc2 = {0.f,0.f,0.f,0.f}, acc3 = {0.f,0.f,0.f,0.f};

#pragma unroll
    for (int bt = 0; bt < 5; ++bt) {
        const int ntap = (bt == 4) ? 1 : 2;
        int4  vv[8];
        float wts[2][4];
        // -- address calc + issue all corner loads for the tap pair --
#pragma unroll
        for (int j = 0; j < 2; ++j) {
            if (j < ntap) {
                int tap = bt * 2 + j;
                // reference semantics: per-corner float-coord validity,
                // clamped gather index
                float py  = offv[2 * tap]     + fy + (float)(tap / 3 - 1);
                float pf  = offv[2 * tap + 1] + fx + (float)(tap % 3 - 1);
                float y0f = floorf(py), x0f = floorf(pf);
                float wy  = py - y0f,   wx  = pf - x0f;
                int   iy0 = (int)y0f,   ix0 = (int)x0f;
                float vy0 = (y0f >=  0.f && y0f <= 127.f) ? 1.f : 0.f;
                float vy1 = (y0f >= -1.f && y0f <= 126.f) ? 1.f : 0.f;
                float vx0 = (x0f >=  0.f && x0f <= 127.f) ? 1.f : 0.f;
                float vx1 = (x0f >= -1.f && x0f <= 126.f) ? 1.f : 0.f;
                int cy0 = min(max(iy0, 0), 127), cy1 = min(max(iy0 + 1, 0), 127);
                int cx0 = min(max(ix0, 0), 127), cx1 = min(max(ix0 + 1, 0), 127);
                wts[j][0] = (1.f - wy) * (1.f - wx) * vy0 * vx0;
                wts[j][1] = (1.f - wy) * wx * vy0 * vx1;
                wts[j][2] = wy * (1.f - wx) * vy1 * vx0;
                wts[j][3] = wy * wx * vy1 * vx1;
                vv[j * 4 + 0] = *(const int4*)(xb + ((cy0 << 7) + cx0) * 64 + koff);
                vv[j * 4 + 1] = *(const int4*)(xb + ((cy0 << 7) + cx1) * 64 + koff);
                vv[j * 4 + 2] = *(const int4*)(xb + ((cy1 << 7) + cx0) * 64 + koff);
                vv[j * 4 + 3] = *(const int4*)(xb + ((cy1 << 7) + cx1) * 64 + koff);
            }
        }
        __builtin_amdgcn_sched_barrier(0);   // keep loads above consumers
        // -- comb + MFMA for the pair --
#pragma unroll
        for (int j = 0; j < 2; ++j) {
            if (j < ntap) {
                int tap = bt * 2 + j;
                bf16x8 a = comb4(vv[j * 4 + 0], vv[j * 4 + 1],
                                 vv[j * 4 + 2], vv[j * 4 + 3],
                                 wts[j][0], wts[j][1], wts[j][2], wts[j][3]);
                acc0 = MFMA(a, WD[((tap * 8 + ks * 4 + 0) << 6) + lane], acc0, 0, 0, 0);
                acc1 = MFMA(a, WD[((tap * 8 + ks * 4 + 1) << 6) + lane], acc1, 0, 0, 0);
                acc2 = MFMA(a, WD[((tap * 8 + ks * 4 + 2) << 6) + lane], acc2, 0, 0, 0);
                acc3 = MFMA(a, WD[((tap * 8 + ks * 4 + 3) << 6) + lane], acc3, 0, 0, 0);
            }
        }
    }

    // ---- epilogue: combine ks halves in LDS, store, BN partials ----
    if (ks == 1) {
#pragma unroll
        for (int r = 0; r < 4; ++r) {
            so[ 0 + mi][m0 + quad * 4 + r] = acc0[r];
            so[16 + mi][m0 + quad * 4 + r] = acc1[r];
            so[32 + mi][m0 + quad * 4 + r] = acc2[r];
            so[48 + mi][m0 + quad * 4 + r] = acc3[r];
        }
    }
    __syncthreads();
    if (ks == 0) {
#pragma unroll
        for (int r = 0; r < 4; ++r) {
            so[ 0 + mi][m0 + quad * 4 + r] += acc0[r];
            so[16 + mi][m0 + quad * 4 + r] += acc1[r];
            so[32 + mi][m0 + quad * 4 + r] += acc2[r];
            so[48 + mi][m0 + quad * 4 + r] += acc3[r];
        }
    }
    __syncthreads();

    int n  = tid >> 2;
    int c4 = tid & 3;
    int pl = c4 * 8;
    float s = 0.f, q = 0.f;
    float vals[8];
#pragma unroll
    for (int i = 0; i < 8; ++i) {
        float v = so[n][pl + i];
        vals[i] = v;
        s += v;
        q = fmaf(v, v, q);
    }
    float* dst = out + (size_t)(b * 64 + n) * HW + (y << 7) + x0 + pl;
    *(float4*)dst       = make_float4(vals[0], vals[1], vals[2], vals[3]);
    *(float4*)(dst + 4) = make_float4(vals[4], vals[5], vals[6], vals[7]);

    s += __shfl_xor(s, 1); s += __shfl_xor(s, 2);
    q += __shfl_xor(q, 1); q += __shfl_xor(q, 2);
    if (c4 == 0) {                          // per-XCD bin: 8x less contention
        float* sb = sums + (blockIdx.x & 7) * 128;
        atomicAdd(&sb[n], s);
        atomicAdd(&sb[64 + n], q);
    }
}

// ---------------------------------------------------------------------------
// k_bn: BN (biased var) + gamma/beta + ReLU, in place over d_out.
// sums has 8 per-XCD bins of [64 sum | 64 sumsq].
// ---------------------------------------------------------------------------
__global__ __launch_bounds__(256)
void k_bn(float* __restrict__ out, const float* __restrict__ sums,
          const float* __restrict__ gamma, const float* __restrict__ beta) {
    int i4 = blockIdx.x * 256 + threadIdx.x;
    int e  = i4 << 2;
    int o  = (e >> 14) & 63;
    float sm = 0.f, sq = 0.f;
#pragma unroll
    for (int s8 = 0; s8 < 8; ++s8) {
        sm += sums[s8 * 128 + o];
        sq += sums[s8 * 128 + 64 + o];
    }
    const float n = 65536.f;
    float mean = sm / n;
    float var  = fmaxf(sq / n - mean * mean, 0.f);
    float sc   = rsqrtf(var + 1e-5f) * gamma[o];
    float sh   = beta[o] - mean * sc;
    float4 v = *(const float4*)&out[e];
    v.x = fmaxf(fmaf(v.x, sc, sh), 0.f);
    v.y = fmaxf(fmaf(v.y, sc, sh), 0.f);
    v.z = fmaxf(fmaf(v.z, sc, sh), 0.f);
    v.w = fmaxf(fmaf(v.w, sc, sh), 0.f);
    *(float4*)&out[e] = v;
}

// ---------------------------------------------------------------------------
// Workspace layout (bytes):
//   xh   : [0, 8388608)            NHWC bf16 x
//   wtd  : [8388608, 8462336)      72 B-frags dcn weights
//   wto  : [8462336, 8499200)      36 B-frags offset weights
//   sums : [8499200, 8503296)      BN partials, 8 XCD bins (zeroed by k_pre)
// ---------------------------------------------------------------------------
extern "C" void kernel_launch(void* const* d_in, const int* in_sizes, int n_in,
                              void* d_out, int out_size, void* d_ws, size_t ws_size,
                              hipStream_t stream) {
    const float* x     = (const float*)d_in[0];
    const float* ow    = (const float*)d_in[1];
    const float* ob    = (const float*)d_in[2];
    const float* dw    = (const float*)d_in[3];
    const float* gamma = (const float*)d_in[4];
    const float* beta  = (const float*)d_in[5];
    float* out = (float*)d_out;
    char*  wsb = (char*)d_ws;
    u16*   xh   = (u16*)wsb;
    u16*   wtd  = (u16*)(wsb + 8388608);
    u16*   wto  = (u16*)(wsb + 8462336);
    float* sums = (float*)(wsb + 8499200);

    k_pre<<<540, 256, 0, stream>>>(x, dw, ow, xh, wtd, wto, sums);
    k_main<<<2048, 256, 0, stream>>>(xh, wto, wtd, ob, out, sums);
    k_bn<<<4096, 256, 0, stream>>>(out, sums, gamma, beta);
}

// Round 10
// 144.906 us; speedup vs baseline: 1.0161x; 1.0161x over previous
//
#include <hip/hip_runtime.h>

// Problem constants (B=4, C_IN=C_OUT=64, H=W=128, K=3, stride=1, pad=1)
// Harness I/O fp32. Internally: NHWC bf16 x, bf16 MFMA for both convs.
// Round ledger: total ~= k_main + ~15us (k_pre+k_bn) + ~65-70us fixed harness
// reset/graph overhead.  k_main is the only real lever.
// R9 post-mortem: VALU floor ~18us/wave-set; stalls are shared-resource (L1
// thrash by 55KB/wave B-frag streaming).  This round: nt loads for B-frags.
#define HW   16384
#define NPX  65536

typedef unsigned short u16;
typedef unsigned int   u32;
typedef short bf16x8 __attribute__((ext_vector_type(8)));
typedef float f32x4  __attribute__((ext_vector_type(4)));

__device__ __forceinline__ u16 f2b(float f) {               // fp32->bf16 RNE
    u32 u = __float_as_uint(f);
    return (u16)((u + 0x7FFFu + ((u >> 16) & 1u)) >> 16);
}
__device__ __forceinline__ float blo(u32 u) { return __uint_as_float(u << 16); }
__device__ __forceinline__ float bhi(u32 u) { return __uint_as_float(u & 0xffff0000u); }

// bilinear blend of one u32 (2 bf16 channels) x 4 corners -> packed bf16 pair
// pack via v_perm_b32 (round-half-up, matches prior rounds' accepted error)
__device__ __forceinline__ u32 comb(u32 a00, u32 a01, u32 a10, u32 a11,
                                    float w00, float w01, float w10, float w11) {
    float lo = fmaf(w11, blo(a11), fmaf(w10, blo(a10), fmaf(w01, blo(a01), w00 * blo(a00))));
    float hi = fmaf(w11, bhi(a11), fmaf(w10, bhi(a10), fmaf(w01, bhi(a01), w00 * bhi(a00))));
    return __builtin_amdgcn_perm(__float_as_uint(hi) + 0x8000u,
                                 __float_as_uint(lo) + 0x8000u, 0x07060302u);
}

#define MFMA __builtin_amdgcn_mfma_f32_16x16x32_bf16
#define NTL(p) __builtin_nontemporal_load(p)

// ---------------------------------------------------------------------------
// k_pre: blocks [0,512): NCHW fp32 -> NHWC bf16, 128-px tiles (coalesced).
// Blocks [512,539): weight prep to B-frag-linear bf16
//   (frag: lane holds B[k=(lane>>4)*8+j][n=lane&15], j=0..7).
//   wtd: dcn_w,    fid = tap*8 + ks*4 + nt  (72 frags, N=64)
//   wto: offset_w, fid = tap*4 + ks*2 + nt  (36 frags, N=32, n>=18 -> 0)
// Block 539: zero BN partial bins.
// ---------------------------------------------------------------------------
__global__ __launch_bounds__(256)
void k_pre(const float* __restrict__ x, const float* __restrict__ dw,
           const float* __restrict__ ow, u16* __restrict__ xh,
           u16* __restrict__ wtd, u16* __restrict__ wto,
           float* __restrict__ sums) {
    int tid = threadIdx.x;
    int bid = blockIdx.x;
    if (bid >= 512) {
        if (bid == 539) {
            for (int i = tid; i < 1024; i += 256) sums[i] = 0.f;
            return;
        }
        int gid = (bid - 512) * 256 + tid;       // ---- weight prep ----
        if (gid >= 108 * 64) return;
        int fid = gid >> 6, lane = gid & 63;
        int mi = lane & 15, quad = lane >> 4;
        u32 w[4];
        if (fid < 72) {
            int tap = fid >> 3, rem = fid & 7;
            int ks = rem >> 2, nt = rem & 3;
            int n = nt * 16 + mi;
            int cb = ks * 32 + quad * 8;
#pragma unroll
            for (int i = 0; i < 4; ++i) {
                u32 lo = f2b(dw[(n * 64 + cb + 2 * i) * 9 + tap]);
                u32 hi = f2b(dw[(n * 64 + cb + 2 * i + 1) * 9 + tap]);
                w[i] = lo | (hi << 16);
            }
            *((int4*)wtd + (fid << 6) + lane) = make_int4(w[0], w[1], w[2], w[3]);
        } else {
            int f2 = fid - 72;
            int tap = f2 >> 2, rem = f2 & 3;
            int ks = rem >> 1, nt = rem & 1;
            int n = nt * 16 + mi;
            int cb = ks * 32 + quad * 8;
#pragma unroll
            for (int i = 0; i < 4; ++i) {
                u32 lo = (n < 18) ? f2b(ow[(n * 64 + cb + 2 * i) * 9 + tap]) : 0u;
                u32 hi = (n < 18) ? f2b(ow[(n * 64 + cb + 2 * i + 1) * 9 + tap]) : 0u;
                w[i] = lo | (hi << 16);
            }
            *((int4*)wto + (f2 << 6) + lane) = make_int4(w[0], w[1], w[2], w[3]);
        }
        return;
    }
    // ---- NCHW fp32 -> NHWC bf16, 128-px tile ----
    __shared__ u16 tile[64][138];
    int p0  = bid * 128;
    int b   = p0 >> 14;
    int hw0 = p0 & (HW - 1);
    int pxq = (tid & 31) * 4;
    int rr  = tid >> 5;
    const float* src = x + (size_t)b * 64 * HW + hw0 + pxq;
#pragma unroll
    for (int i = 0; i < 8; ++i) {
        int c = i * 8 + rr;
        float4 v = *(const float4*)(src + (size_t)c * HW);
        ushort4 h;
        h.x = f2b(v.x); h.y = f2b(v.y); h.z = f2b(v.z); h.w = f2b(v.w);
        *(ushort4*)&tile[c][pxq] = h;
    }
    __syncthreads();
    int sub = tid & 3;
#pragma unroll
    for (int j = 0; j < 2; ++j) {
        int px = j * 64 + (tid >> 2);
        u32 w[8];
#pragma unroll
        for (int t = 0; t < 8; ++t) {
            int c = sub * 16 + 2 * t;
            w[t] = (u32)tile[c][px] | ((u32)tile[c + 1][px] << 16);
        }
        u16* dst = xh + (size_t)(p0 + px) * 64 + sub * 16;
        *(int4*)dst       = make_int4(w[0], w[1], w[2], w[3]);
        *(int4*)(dst + 8) = make_int4(w[4], w[5], w[6], w[7]);
    }
}

// ---------------------------------------------------------------------------
// k_main: FUSED offset conv + deformable conv, ks-split (R6 structure — the
// best-measured variant), with NON-TEMPORAL B-frag loads so the 55KB/wave
// weight stream does not evict the x-gather window from L1.
// 2048 blocks x 256 thr; block = 32 px.  Wave = (ks, px-half): 16 px x 64
// out x 32 ch (K=288 split across ks).
// ---------------------------------------------------------------------------
__global__ __launch_bounds__(256, 6)
void k_main(const u16* __restrict__ xh, const u16* __restrict__ wto,
            const u16* __restrict__ wtd, const float* __restrict__ ob,
            float* __restrict__ out, float* __restrict__ sums) {
    __shared__ float offs[2][18][34];
    __shared__ float so[64][33];

    int tid = threadIdx.x;
    int vb  = (blockIdx.x & 7) * 256 + (blockIdx.x >> 3);   // XCD-contig
    int p0  = vb * 32;
    int b   = p0 >> 14;
    int hw0 = p0 & (HW - 1);
    int y   = hw0 >> 7;
    int x0  = hw0 & 127;
    int wave = tid >> 6, lane = tid & 63;
    int mi = lane & 15, quad = lane >> 4;
    int ks = wave >> 1;
    int m0 = (wave & 1) << 4;
    int xcol = x0 + m0 + mi;
    int koff = ks * 32 + quad * 8;
    const u16* xb = xh + (size_t)b * HW * 64;
    const bf16x8* WO = (const bf16x8*)wto;
    const bf16x8* WD = (const bf16x8*)wtd;

    // ---- phase 1: offset conv partial (this ks half) ----
    f32x4 oa0 = {0.f, 0.f, 0.f, 0.f}, oa1 = {0.f, 0.f, 0.f, 0.f};
#pragma unroll
    for (int tap = 0; tap < 9; ++tap) {
        int yy = y + tap / 3 - 1;
        int xx = xcol + tap % 3 - 1;
        int yc = min(max(yy, 0), 127), xc = min(max(xx, 0), 127);
        bool valid = ((unsigned)yy < 128u) && ((unsigned)xx < 128u);
        int4 a = *(const int4*)(xb + ((yc << 7) + xc) * 64 + koff);
        if (!valid) a = make_int4(0, 0, 0, 0);
        bf16x8 af = __builtin_bit_cast(bf16x8, a);
        oa0 = MFMA(af, NTL(&WO[((tap * 4 + ks * 2 + 0) << 6) + lane]), oa0, 0, 0, 0);
        oa1 = MFMA(af, NTL(&WO[((tap * 4 + ks * 2 + 1) << 6) + lane]), oa1, 0, 0, 0);
    }
    {   // C layout: col = lane&15 = n, row = quad*4+r = px-in-wave-tile
        float bias0 = (ks == 0) ? ob[mi] : 0.f;
#pragma unroll
        for (int r = 0; r < 4; ++r)
            offs[ks][mi][m0 + quad * 4 + r] = oa0[r] + bias0;
        if (mi < 2) {
            float bias1 = (ks == 0) ? ob[16 + mi] : 0.f;
#pragma unroll
            for (int r = 0; r < 4; ++r)
                offs[ks][16 + mi][m0 + quad * 4 + r] = oa1[r] + bias1;
        }
    }
    __syncthreads();

    // ---- phase 2: deformable conv (this ks half) ----
    int pxl = m0 + mi;
    float offv[18];
#pragma unroll
    for (int m = 0; m < 18; ++m)
        offv[m] = offs[0][m][pxl] + offs[1][m][pxl];

    float fy = (float)y, fx = (float)xcol;
    f32x4 acc0 = {0.f,0.f,0.f,0.f}, acc1 = {0.f,0.f,0.f,0.f};
    f32x4 acc2 = {0.f,0.f,0.f,0.f}, acc3 = {0.f,0.f,0.f,0.f};

#pragma unroll
    for (int tap = 0; tap < 9; ++tap) {
        // reference semantics: per-corner float-coord validity, clamped gather
        float py  = offv[2 * tap]     + fy + (float)(tap / 3 - 1);
        float pf  = offv[2 * tap + 1] + fx + (float)(tap % 3 - 1);
        float y0f = floorf(py), x0f = floorf(pf);
        float wy  = py - y0f,   wx  = pf - x0f;
        int   iy0 = (int)y0f,   ix0 = (int)x0f;
        float vy0 = (y0f >=  0.f && y0f <= 127.f) ? 1.f : 0.f;
        float vy1 = (y0f >= -1.f && y0f <= 126.f) ? 1.f : 0.f;
        float vx0 = (x0f >=  0.f && x0f <= 127.f) ? 1.f : 0.f;
        float vx1 = (x0f >= -1.f && x0f <= 126.f) ? 1.f : 0.f;
        int cy0 = min(max(iy0, 0), 127), cy1 = min(max(iy0 + 1, 0), 127);
        int cx0 = min(max(ix0, 0), 127), cx1 = min(max(ix0 + 1, 0), 127);
        float w00 = (1.f - wy) * (1.f - wx) * vy0 * vx0;
        float w01 = (1.f - wy) * wx * vy0 * vx1;
        float w10 = wy * (1.f - wx) * vy1 * vx0;
        float w11 = wy * wx * vy1 * vx1;
        int4 v00 = *(const int4*)(xb + ((cy0 << 7) + cx0) * 64 + koff);
        int4 v01 = *(const int4*)(xb + ((cy0 << 7) + cx1) * 64 + koff);
        int4 v10 = *(const int4*)(xb + ((cy1 << 7) + cx0) * 64 + koff);
        int4 v11 = *(const int4*)(xb + ((cy1 << 7) + cx1) * 64 + koff);
        int4 r;
        r.x = comb(v00.x, v01.x, v10.x, v11.x, w00, w01, w10, w11);
        r.y = comb(v00.y, v01.y, v10.y, v11.y, w00, w01, w10, w11);
        r.z = comb(v00.z, v01.z, v10.z, v11.z, w00, w01, w10, w11);
        r.w = comb(v00.w, v01.w, v10.w, v11.w, w00, w01, w10, w11);
        bf16x8 a = __builtin_bit_cast(bf16x8, r);
        acc0 = MFMA(a, NTL(&WD[((tap * 8 + ks * 4 + 0) << 6) + lane]), acc0, 0, 0, 0);
        acc1 = MFMA(a, NTL(&WD[((tap * 8 + ks * 4 + 1) << 6) + lane]), acc1, 0, 0, 0);
        acc2 = MFMA(a, NTL(&WD[((tap * 8 + ks * 4 + 2) << 6) + lane]), acc2, 0, 0, 0);
        acc3 = MFMA(a, NTL(&WD[((tap * 8 + ks * 4 + 3) << 6) + lane]), acc3, 0, 0, 0);
    }

    // ---- epilogue: combine ks halves in LDS, store, BN partials ----
    if (ks == 1) {
#pragma unroll
        for (int r = 0; r < 4; ++r) {
            so[ 0 + mi][m0 + quad * 4 + r] = acc0[r];
            so[16 + mi][m0 + quad * 4 + r] = acc1[r];
            so[32 + mi][m0 + quad * 4 + r] = acc2[r];
            so[48 + mi][m0 + quad * 4 + r] = acc3[r];
        }
    }
    __syncthreads();
    if (ks == 0) {
#pragma unroll
        for (int r = 0; r < 4; ++r) {
            so[ 0 + mi][m0 + quad * 4 + r] += acc0[r];
            so[16 + mi][m0 + quad * 4 + r] += acc1[r];
            so[32 + mi][m0 + quad * 4 + r] += acc2[r];
            so[48 + mi][m0 + quad * 4 + r] += acc3[r];
        }
    }
    __syncthreads();

    int n  = tid >> 2;
    int c4 = tid & 3;
    int pl = c4 * 8;
    float s = 0.f, q = 0.f;
    float vals[8];
#pragma unroll
    for (int i = 0; i < 8; ++i) {
        float v = so[n][pl + i];
        vals[i] = v;
        s += v;
        q = fmaf(v, v, q);
    }
    float* dst = out + (size_t)(b * 64 + n) * HW + (y << 7) + x0 + pl;
    *(float4*)dst       = make_float4(vals[0], vals[1], vals[2], vals[3]);
    *(float4*)(dst + 4) = make_float4(vals[4], vals[5], vals[6], vals[7]);

    s += __shfl_xor(s, 1); s += __shfl_xor(s, 2);
    q += __shfl_xor(q, 1); q += __shfl_xor(q, 2);
    if (c4 == 0) {                          // per-XCD bin: 8x less contention
        float* sb = sums + (blockIdx.x & 7) * 128;
        atomicAdd(&sb[n], s);
        atomicAdd(&sb[64 + n], q);
    }
}

// ---------------------------------------------------------------------------
// k_bn: BN (biased var) + gamma/beta + ReLU, in place over d_out.
// sums has 8 per-XCD bins of [64 sum | 64 sumsq].
// ---------------------------------------------------------------------------
__global__ __launch_bounds__(256)
void k_bn(float* __restrict__ out, const float* __restrict__ sums,
          const float* __restrict__ gamma, const float* __restrict__ beta) {
    int i4 = blockIdx.x * 256 + threadIdx.x;
    int e  = i4 << 2;
    int o  = (e >> 14) & 63;
    float sm = 0.f, sq = 0.f;
#pragma unroll
    for (int s8 = 0; s8 < 8; ++s8) {
        sm += sums[s8 * 128 + o];
        sq += sums[s8 * 128 + 64 + o];
    }
    const float n = 65536.f;
    float mean = sm / n;
    float var  = fmaxf(sq / n - mean * mean, 0.f);
    float sc   = rsqrtf(var + 1e-5f) * gamma[o];
    float sh   = beta[o] - mean * sc;
    float4 v = *(const float4*)&out[e];
    v.x = fmaxf(fmaf(v.x, sc, sh), 0.f);
    v.y = fmaxf(fmaf(v.y, sc, sh), 0.f);
    v.z = fmaxf(fmaf(v.z, sc, sh), 0.f);
    v.w = fmaxf(fmaf(v.w, sc, sh), 0.f);
    *(float4*)&out[e] = v;
}

// ---------------------------------------------------------------------------
// Workspace layout (bytes):
//   xh   : [0, 8388608)            NHWC bf16 x
//   wtd  : [8388608, 8462336)      72 B-frags dcn weights
//   wto  : [8462336, 8499200)      36 B-frags offset weights
//   sums : [8499200, 8503296)      BN partials, 8 XCD bins (zeroed by k_pre)
// ---------------------------------------------------------------------------
extern "C" void kernel_launch(void* const* d_in, const int* in_sizes, int n_in,
                              void* d_out, int out_size, void* d_ws, size_t ws_size,
                              hipStream_t stream) {
    const float* x     = (const float*)d_in[0];
    const float* ow    = (const float*)d_in[1];
    const float* ob    = (const float*)d_in[2];
    const float* dw    = (const float*)d_in[3];
    const float* gamma = (const float*)d_in[4];
    const float* beta  = (const float*)d_in[5];
    float* out = (float*)d_out;
    char*  wsb = (char*)d_ws;
    u16*   xh   = (u16*)wsb;
    u16*   wtd  = (u16*)(wsb + 8388608);
    u16*   wto  = (u16*)(wsb + 8462336);
    float* sums = (float*)(wsb + 8499200);

    k_pre<<<540, 256, 0, stream>>>(x, dw, ow, xh, wtd, wto, sums);
    k_main<<<2048, 256, 0, stream>>>(xh, wto, wtd, ob, out, sums);
    k_bn<<<4096, 256, 0, stream>>>(out, sums, gamma, beta);
}

// Round 13
// 123.352 us; speedup vs baseline: 1.1937x; 1.1747x over previous
//
#include <hip/hip_runtime.h>

// Problem constants (B=4, C_IN=C_OUT=64, H=W=128, K=3, stride=1, pad=1)
// Harness I/O fp32. Internally: NHWC bf16 x, bf16 MFMA for both convs.
// Ledger: total ~= k_main + ~15us (k_pre+k_bn) + ~65us fixed harness
// overhead.  k_main plateaued 59-73us R4-R12.  Falsified: occupancy, HBM BW,
// MFMA rate, L1 thrash; asm pipelines: deleted/rejected/corrupt (R7-R12).
// R13: move gathers to an LDS-staged 5x36 window (offsets are tiny: std
// ~0.24), per-lane global fallback for the rare out-of-window corner.
#define HW   16384
#define NPX  65536

typedef unsigned short u16;
typedef unsigned int   u32;
typedef short bf16x8 __attribute__((ext_vector_type(8)));
typedef float f32x4  __attribute__((ext_vector_type(4)));

__device__ __forceinline__ u16 f2b(float f) {               // fp32->bf16 RNE
    u32 u = __float_as_uint(f);
    return (u16)((u + 0x7FFFu + ((u >> 16) & 1u)) >> 16);
}
__device__ __forceinline__ float blo(u32 u) { return __uint_as_float(u << 16); }
__device__ __forceinline__ float bhi(u32 u) { return __uint_as_float(u & 0xffff0000u); }

// bilinear blend of one u32 (2 bf16 channels) x 4 corners -> packed bf16 pair
__device__ __forceinline__ u32 comb(u32 a00, u32 a01, u32 a10, u32 a11,
                                    float w00, float w01, float w10, float w11) {
    float lo = fmaf(w11, blo(a11), fmaf(w10, blo(a10), fmaf(w01, blo(a01), w00 * blo(a00))));
    float hi = fmaf(w11, bhi(a11), fmaf(w10, bhi(a10), fmaf(w01, bhi(a01), w00 * bhi(a00))));
    return __builtin_amdgcn_perm(__float_as_uint(hi) + 0x8000u,
                                 __float_as_uint(lo) + 0x8000u, 0x07060302u);
}

#define MFMA __builtin_amdgcn_mfma_f32_16x16x32_bf16

// ---------------------------------------------------------------------------
// k_pre: blocks [0,512): NCHW fp32 -> NHWC bf16, 128-px tiles (coalesced).
// Blocks [512,539): weight prep to B-frag-linear bf16
//   (frag: lane holds B[k=(lane>>4)*8+j][n=lane&15], j=0..7).
//   wtd: dcn_w,    fid = tap*8 + ks*4 + nt  (72 frags, N=64)
//   wto: offset_w, fid = tap*4 + ks*2 + nt  (36 frags, N=32, n>=18 -> 0)
// Block 539: zero BN partial bins.
// ---------------------------------------------------------------------------
__global__ __launch_bounds__(256)
void k_pre(const float* __restrict__ x, const float* __restrict__ dw,
           const float* __restrict__ ow, u16* __restrict__ xh,
           u16* __restrict__ wtd, u16* __restrict__ wto,
           float* __restrict__ sums) {
    int tid = threadIdx.x;
    int bid = blockIdx.x;
    if (bid >= 512) {
        if (bid == 539) {
            for (int i = tid; i < 1024; i += 256) sums[i] = 0.f;
            return;
        }
        int gid = (bid - 512) * 256 + tid;       // ---- weight prep ----
        if (gid >= 108 * 64) return;
        int fid = gid >> 6, lane = gid & 63;
        int mi = lane & 15, quad = lane >> 4;
        u32 w[4];
        if (fid < 72) {
            int tap = fid >> 3, rem = fid & 7;
            int ks = rem >> 2, nt = rem & 3;
            int n = nt * 16 + mi;
            int cb = ks * 32 + quad * 8;
#pragma unroll
            for (int i = 0; i < 4; ++i) {
                u32 lo = f2b(dw[(n * 64 + cb + 2 * i) * 9 + tap]);
                u32 hi = f2b(dw[(n * 64 + cb + 2 * i + 1) * 9 + tap]);
                w[i] = lo | (hi << 16);
            }
            *((int4*)wtd + (fid << 6) + lane) = make_int4(w[0], w[1], w[2], w[3]);
        } else {
            int f2 = fid - 72;
            int tap = f2 >> 2, rem = f2 & 3;
            int ks = rem >> 1, nt = rem & 1;
            int n = nt * 16 + mi;
            int cb = ks * 32 + quad * 8;
#pragma unroll
            for (int i = 0; i < 4; ++i) {
                u32 lo = (n < 18) ? f2b(ow[(n * 64 + cb + 2 * i) * 9 + tap]) : 0u;
                u32 hi = (n < 18) ? f2b(ow[(n * 64 + cb + 2 * i + 1) * 9 + tap]) : 0u;
                w[i] = lo | (hi << 16);
            }
            *((int4*)wto + (f2 << 6) + lane) = make_int4(w[0], w[1], w[2], w[3]);
        }
        return;
    }
    // ---- NCHW fp32 -> NHWC bf16, 128-px tile ----
    __shared__ u16 tile[64][138];
    int p0  = bid * 128;
    int b   = p0 >> 14;
    int hw0 = p0 & (HW - 1);
    int pxq = (tid & 31) * 4;
    int rr  = tid >> 5;
    const float* src = x + (size_t)b * 64 * HW + hw0 + pxq;
#pragma unroll
    for (int i = 0; i < 8; ++i) {
        int c = i * 8 + rr;
        float4 v = *(const float4*)(src + (size_t)c * HW);
        ushort4 h;
        h.x = f2b(v.x); h.y = f2b(v.y); h.z = f2b(v.z); h.w = f2b(v.w);
        *(ushort4*)&tile[c][pxq] = h;
    }
    __syncthreads();
    int sub = tid & 3;
#pragma unroll
    for (int j = 0; j < 2; ++j) {
        int px = j * 64 + (tid >> 2);
        u32 w[8];
#pragma unroll
        for (int t = 0; t < 8; ++t) {
            int c = sub * 16 + 2 * t;
            w[t] = (u32)tile[c][px] | ((u32)tile[c + 1][px] << 16);
        }
        u16* dst = xh + (size_t)(p0 + px) * 64 + sub * 16;
        *(int4*)dst       = make_int4(w[0], w[1], w[2], w[3]);
        *(int4*)(dst + 8) = make_int4(w[4], w[5], w[6], w[7]);
    }
}

// ---------------------------------------------------------------------------
// k_main: FUSED offset conv + deformable conv, ks-split, with an LDS-staged
// gather window.  Block = 32 px of one row; window = rows y-2..y+2 x cols
// x0-2..x0+33, one 128B NHWC record per px padded to 144B (per-lane col
// stride = 9x16B -> 2-way bank aliasing, free).  Staging is fully coalesced.
// Phase 1 taps are provably in-window (ds_read only).  Phase 2 corners are
// in-window unless |offset|>~1 (prob ~1e-5): per-lane exec-masked global
// fallback keeps correctness unconditional.
// 2048 blocks x 256 thr; wave = (ks, px-half): 16 px x 64 out x 32 ch.
// ---------------------------------------------------------------------------
__global__ __launch_bounds__(256, 4)
void k_main(const u16* __restrict__ xh, const u16* __restrict__ wto,
            const u16* __restrict__ wtd, const float* __restrict__ ob,
            float* __restrict__ out, float* __restrict__ sums) {
    __shared__ __align__(16) char win[25920];   // 5*36 records * 144B
    __shared__ float offs[2][18][34];
    __shared__ float so[64][33];

    int tid = threadIdx.x;
    int vb  = (blockIdx.x & 7) * 256 + (blockIdx.x >> 3);   // XCD-contig
    int p0  = vb * 32;
    int b   = p0 >> 14;
    int hw0 = p0 & (HW - 1);
    int y   = hw0 >> 7;
    int x0  = hw0 & 127;
    int wave = tid >> 6, lane = tid & 63;
    int mi = lane & 15, quad = lane >> 4;
    int ks = wave >> 1;
    int m0 = (wave & 1) << 4;
    int xcol = x0 + m0 + mi;
    int koffu = ks * 32 + quad * 8;           // u16 offset within record
    int boff  = ks * 64 + quad * 16;          // byte offset within record
    int ywin = y - 2, xwin = x0 - 2;
    const u16* xb = xh + (size_t)b * HW * 64;
    const bf16x8* WO = (const bf16x8*)wto;
    const bf16x8* WD = (const bf16x8*)wtd;

    // ---- stage the window (coalesced, 16B/lane, clamp-skipped edges) ----
#pragma unroll
    for (int wr = 0; wr < 5; ++wr) {
        int r = ywin + wr;
        if ((unsigned)r < 128u) {
            for (int u = tid; u < 288; u += 256) {     // 36 records x 8 chunks
                int wc = u >> 3, ch = u & 7;
                int c = xwin + wc;
                if ((unsigned)c < 128u)
                    *(int4*)(win + (wr * 36 + wc) * 144 + ch * 16) =
                        *(const int4*)(xb + (((r << 7) + c) << 6) + ch * 8);
            }
        }
    }
    __syncthreads();

    // ---- phase 1: offset conv partial (this ks half) — all from LDS ----
    f32x4 oa0 = {0.f, 0.f, 0.f, 0.f}, oa1 = {0.f, 0.f, 0.f, 0.f};
#pragma unroll
    for (int tap = 0; tap < 9; ++tap) {
        int yy = y + tap / 3 - 1;
        int xx = xcol + tap % 3 - 1;
        int yc = min(max(yy, 0), 127), xc = min(max(xx, 0), 127);
        bool valid = ((unsigned)yy < 128u) && ((unsigned)xx < 128u);
        int wr = yc - ywin, wc = xc - xwin;   // provably in [0,5)x[0,36)
        int4 a = *(const int4*)(win + (wr * 36 + wc) * 144 + boff);
        if (!valid) a = make_int4(0, 0, 0, 0);
        bf16x8 af = __builtin_bit_cast(bf16x8, a);
        oa0 = MFMA(af, WO[((tap * 4 + ks * 2 + 0) << 6) + lane], oa0, 0, 0, 0);
        oa1 = MFMA(af, WO[((tap * 4 + ks * 2 + 1) << 6) + lane], oa1, 0, 0, 0);
    }
    {   // C layout: col = lane&15 = n, row = quad*4+r = px-in-wave-tile
        float bias0 = (ks == 0) ? ob[mi] : 0.f;
#pragma unroll
        for (int r = 0; r < 4; ++r)
            offs[ks][mi][m0 + quad * 4 + r] = oa0[r] + bias0;
        if (mi < 2) {
            float bias1 = (ks == 0) ? ob[16 + mi] : 0.f;
#pragma unroll
            for (int r = 0; r < 4; ++r)
                offs[ks][16 + mi][m0 + quad * 4 + r] = oa1[r] + bias1;
        }
    }
    __syncthreads();

    // ---- phase 2: deformable conv (this ks half), LDS gathers ----
    int pxl = m0 + mi;
    float offv[18];
#pragma unroll
    for (int m = 0; m < 18; ++m)
        offv[m] = offs[0][m][pxl] + offs[1][m][pxl];

    float fy = (float)y, fx = (float)xcol;
    f32x4 acc0 = {0.f,0.f,0.f,0.f}, acc1 = {0.f,0.f,0.f,0.f};
    f32x4 acc2 = {0.f,0.f,0.f,0.f}, acc3 = {0.f,0.f,0.f,0.f};

    // per-lane corner read: LDS window, global fallback (exec-masked, rare)
    auto rd = [&](int cy, int cx) -> int4 {
        int wr = cy - ywin, wc = cx - xwin;
        int4 v;
        if (((unsigned)wr < 5u) && ((unsigned)wc < 36u)) {
            v = *(const int4*)(win + (wr * 36 + wc) * 144 + boff);
        } else {
            v = *(const int4*)(xb + (((cy << 7) + cx) << 6) + koffu);
        }
        return v;
    };

#pragma unroll
    for (int tap = 0; tap < 9; ++tap) {
        // reference semantics: per-corner float-coord validity, clamped gather
        float py  = offv[2 * tap]     + fy + (float)(tap / 3 - 1);
        float pf  = offv[2 * tap + 1] + fx + (float)(tap % 3 - 1);
        float y0f = floorf(py), x0f = floorf(pf);
        float wy  = py - y0f,   wx  = pf - x0f;
        int   iy0 = (int)y0f,   ix0 = (int)x0f;
        float vy0 = (y0f >=  0.f && y0f <= 127.f) ? 1.f : 0.f;
        float vy1 = (y0f >= -1.f && y0f <= 126.f) ? 1.f : 0.f;
        float vx0 = (x0f >=  0.f && x0f <= 127.f) ? 1.f : 0.f;
        float vx1 = (x0f >= -1.f && x0f <= 126.f) ? 1.f : 0.f;
        int cy0 = min(max(iy0, 0), 127), cy1 = min(max(iy0 + 1, 0), 127);
        int cx0 = min(max(ix0, 0), 127), cx1 = min(max(ix0 + 1, 0), 127);
        float w00 = (1.f - wy) * (1.f - wx) * vy0 * vx0;
        float w01 = (1.f - wy) * wx * vy0 * vx1;
        float w10 = wy * (1.f - wx) * vy1 * vx0;
        float w11 = wy * wx * vy1 * vx1;
        int4 v00 = rd(cy0, cx0);
        int4 v01 = rd(cy0, cx1);
        int4 v10 = rd(cy1, cx0);
        int4 v11 = rd(cy1, cx1);
        int4 r;
        r.x = comb(v00.x, v01.x, v10.x, v11.x, w00, w01, w10, w11);
        r.y = comb(v00.y, v01.y, v10.y, v11.y, w00, w01, w10, w11);
        r.z = comb(v00.z, v01.z, v10.z, v11.z, w00, w01, w10, w11);
        r.w = comb(v00.w, v01.w, v10.w, v11.w, w00, w01, w10, w11);
        bf16x8 a = __builtin_bit_cast(bf16x8, r);
        int tb = tap * 8 + ks * 4;
        acc0 = MFMA(a, WD[((tb + 0) << 6) + lane], acc0, 0, 0, 0);
        acc1 = MFMA(a, WD[((tb + 1) << 6) + lane], acc1, 0, 0, 0);
        acc2 = MFMA(a, WD[((tb + 2) << 6) + lane], acc2, 0, 0, 0);
        acc3 = MFMA(a, WD[((tb + 3) << 6) + lane], acc3, 0, 0, 0);
    }

    // ---- epilogue: combine ks halves in LDS, store, BN partials ----
    if (ks == 1) {
#pragma unroll
        for (int r = 0; r < 4; ++r) {
            so[ 0 + mi][m0 + quad * 4 + r] = acc0[r];
            so[16 + mi][m0 + quad * 4 + r] = acc1[r];
            so[32 + mi][m0 + quad * 4 + r] = acc2[r];
            so[48 + mi][m0 + quad * 4 + r] = acc3[r];
        }
    }
    __syncthreads();
    if (ks == 0) {
#pragma unroll
        for (int r = 0; r < 4; ++r) {
            so[ 0 + mi][m0 + quad * 4 + r] += acc0[r];
            so[16 + mi][m0 + quad * 4 + r] += acc1[r];
            so[32 + mi][m0 + quad * 4 + r] += acc2[r];
            so[48 + mi][m0 + quad * 4 + r] += acc3[r];
        }
    }
    __syncthreads();

    int n  = tid >> 2;
    int c4 = tid & 3;
    int pl = c4 * 8;
    float s = 0.f, q = 0.f;
    float vals[8];
#pragma unroll
    for (int i = 0; i < 8; ++i) {
        float v = so[n][pl + i];
        vals[i] = v;
        s += v;
        q = fmaf(v, v, q);
    }
    float* dst = out + (size_t)(b * 64 + n) * HW + (y << 7) + x0 + pl;
    *(float4*)dst       = make_float4(vals[0], vals[1], vals[2], vals[3]);
    *(float4*)(dst + 4) = make_float4(vals[4], vals[5], vals[6], vals[7]);

    s += __shfl_xor(s, 1); s += __shfl_xor(s, 2);
    q += __shfl_xor(q, 1); q += __shfl_xor(q, 2);
    if (c4 == 0) {                          // per-XCD bin: 8x less contention
        float* sb = sums + (blockIdx.x & 7) * 128;
        atomicAdd(&sb[n], s);
        atomicAdd(&sb[64 + n], q);
    }
}

// ---------------------------------------------------------------------------
// k_bn: BN (biased var) + gamma/beta + ReLU, in place over d_out.
// sums has 8 per-XCD bins of [64 sum | 64 sumsq].
// ---------------------------------------------------------------------------
__global__ __launch_bounds__(256)
void k_bn(float* __restrict__ out, const float* __restrict__ sums,
          const float* __restrict__ gamma, const float* __restrict__ beta) {
    int i4 = blockIdx.x * 256 + threadIdx.x;
    int e  = i4 << 2;
    int o  = (e >> 14) & 63;
    float sm = 0.f, sq = 0.f;
#pragma unroll
    for (int s8 = 0; s8 < 8; ++s8) {
        sm += sums[s8 * 128 + o];
        sq += sums[s8 * 128 + 64 + o];
    }
    const float n = 65536.f;
    float mean = sm / n;
    float var  = fmaxf(sq / n - mean * mean, 0.f);
    float sc   = rsqrtf(var + 1e-5f) * gamma[o];
    float sh   = beta[o] - mean * sc;
    float4 v = *(const float4*)&out[e];
    v.x = fmaxf(fmaf(v.x, sc, sh), 0.f);
    v.y = fmaxf(fmaf(v.y, sc, sh), 0.f);
    v.z = fmaxf(fmaf(v.z, sc, sh), 0.f);
    v.w = fmaxf(fmaf(v.w, sc, sh), 0.f);
    *(float4*)&out[e] = v;
}

// ---------------------------------------------------------------------------
// Workspace layout (bytes):
//   xh   : [0, 8388608)            NHWC bf16 x
//   wtd  : [8388608, 8462336)      72 B-frags dcn weights
//   wto  : [8462336, 8499200)      36 B-frags offset weights
//   sums : [8499200, 8503296)      BN partials, 8 XCD bins (zeroed by k_pre)
// ---------------------------------------------------------------------------
extern "C" void kernel_launch(void* const* d_in, const int* in_sizes, int n_in,
                              void* d_out, int out_size, void* d_ws, size_t ws_size,
                              hipStream_t stream) {
    const float* x     = (const float*)d_in[0];
    const float* ow    = (const float*)d_in[1];
    const float* ob    = (const float*)d_in[2];
    const float* dw    = (const float*)d_in[3];
    const float* gamma = (const float*)d_in[4];
    const float* beta  = (const float*)d_in[5];
    float* out = (float*)d_out;
    char*  wsb = (char*)d_ws;
    u16*   xh   = (u16*)wsb;
    u16*   wtd  = (u16*)(wsb + 8388608);
    u16*   wto  = (u16*)(wsb + 8462336);
    float* sums = (float*)(wsb + 8499200);

    k_pre<<<540, 256, 0, stream>>>(x, dw, ow, xh, wtd, wto, sums);
    k_main<<<2048, 256, 0, stream>>>(xh, wto, wtd, ob, out, sums);
    k_bn<<<4096, 256, 0, stream>>>(out, sums, gamma, beta);
}